// Round 13
// baseline (2162.730 us; speedup 1.0000x reference)
//
#include <hip/hip_runtime.h>

#define CHUNK 2048

union SMem {
    int   i[2048];        // 8 KB int scratch (sort phase needs 1792)
    float w[2][4096];     // 32 KB transform W double-buffer
};

// Manual grid barrier: all 1024 blocks co-resident (4/CU x 256 CU; VGPR<=128,
// LDS 32 KB -> 5/CU possible). Arrive = ONE device-scope RMW per block; spin =
// relaxed agent-scope atomic LOAD (no line exclusivity -> no XCD ping-pong;
// R12's atomicAdd(cnt,0) RMW-spin cost ~240 us/barrier).
__device__ __forceinline__ void grid_barrier(int* cnt, int gen, int nblk) {
    __syncthreads();
    __threadfence();                       // release
    if (threadIdx.x == 0) {
        atomicAdd(cnt, 1);
        int target = nblk * gen;
        while (__hip_atomic_load(cnt, __ATOMIC_RELAXED, __HIP_MEMORY_SCOPE_AGENT) < target)
            __builtin_amdgcn_s_sleep(8);   // ~512 cyc backoff per poll
    }
    __syncthreads();
    __threadfence();                       // acquire
}

// R10 transform body (4 nodes/thread, 64-row slabs, double-buffered), vb-param'd.
__device__ __forceinline__ void transform_vb(
    float (*wsh)[4096], int vb, int t,
    const float* __restrict__ hin, const float* __restrict__ means,
    const float* __restrict__ wroot, const float* __restrict__ wrel,
    const float* __restrict__ bias, float* __restrict__ hout, int n_nodes)
{
    int gt = vb * 256 + t;
    int g = gt >> 4, q = gt & 15;
    int n0 = g * 4;
    bool active = (n0 < n_nodes);

    {
        const float4* sp = (const float4*)wroot;
        float4* d = (float4*)wsh[0];
#pragma unroll
        for (int i = 0; i < 4; ++i) d[t + i * 256] = sp[t + i * 256];
    }
    float4 acc[4];
    float4 b = {0.f, 0.f, 0.f, 0.f};
    if (active) b = *(const float4*)(bias + q * 4);
#pragma unroll
    for (int i = 0; i < 4; ++i) acc[i] = b;

    const float* hv = hin + (size_t)n0 * 64;
    const float* mv = means + (size_t)n0 * 192;

    for (int s = 0; s < 4; ++s) {
        __syncthreads();
        if (s < 3) {
            const float4* sp = (const float4*)wrel + (size_t)s * 1024;
            float4* d = (float4*)wsh[(s + 1) & 1];
#pragma unroll
            for (int i = 0; i < 4; ++i) d[t + i * 256] = sp[t + i * 256];
        }
        const float* vbase = (s == 0) ? hv : (mv + (s - 1) * 64);
        int vstride = (s == 0) ? 64 : 192;
        const float* wbuf = wsh[s & 1];
        if (active) {
#pragma unroll 4
            for (int k4 = 0; k4 < 16; ++k4) {
                float4 v[4];
#pragma unroll
                for (int i = 0; i < 4; ++i)
                    v[i] = *(const float4*)(vbase + i * vstride + k4 * 4);
#pragma unroll
                for (int kk = 0; kk < 4; ++kk) {
                    float4 w = *(const float4*)(wbuf + (k4 * 4 + kk) * 64 + q * 4);
#pragma unroll
                    for (int i = 0; i < 4; ++i) {
                        float sv = kk == 0 ? v[i].x : kk == 1 ? v[i].y : kk == 2 ? v[i].z : v[i].w;
                        acc[i].x = fmaf(sv, w.x, acc[i].x);
                        acc[i].y = fmaf(sv, w.y, acc[i].y);
                        acc[i].z = fmaf(sv, w.z, acc[i].z);
                        acc[i].w = fmaf(sv, w.w, acc[i].w);
                    }
                }
            }
        }
    }
    if (active) {
        float* o = hout + (size_t)n0 * 64 + q * 4;
#pragma unroll
        for (int i = 0; i < 4; ++i) {
            float4 r = {fmaxf(acc[i].x, 0.f), fmaxf(acc[i].y, 0.f),
                        fmaxf(acc[i].z, 0.f), fmaxf(acc[i].w, 0.f)};
            *(float4*)(o + i * 64) = r;
        }
    }
    __syncthreads();   // wsh reusable
}

// R10 agg body (pair-MLP), one wave per dst, rel-grouped sub-ranges.
__device__ __forceinline__ void agg_dst(
    int wid, int lane,
    const float* __restrict__ hin, const int* __restrict__ rowstartR,
    const int* __restrict__ esort, float* __restrict__ means)
{
    int q = lane >> 4;
    int c = lane & 15;
    int4 rs = *(const int4*)(rowstartR + wid * 4);
#pragma unroll
    for (int r = 0; r < 3; ++r) {
        int sR = (r == 0) ? rs.x : (r == 1) ? rs.y : rs.z;
        int eR = (r == 0) ? rs.y : (r == 1) ? rs.z : rs.w;
        float4 a = {0.f, 0.f, 0.f, 0.f};
        float4 b = {0.f, 0.f, 0.f, 0.f};
        int i = sR + 2 * q;
        for (; i + 2 <= eR; i += 8) {
            int p0 = esort[i];
            int p1 = esort[i + 1];
            float4 v0 = *(const float4*)(hin + (size_t)(p0 & 0xFFFF) * 64 + c * 4);
            float4 v1 = *(const float4*)(hin + (size_t)(p1 & 0xFFFF) * 64 + c * 4);
            a.x += v0.x; a.y += v0.y; a.z += v0.z; a.w += v0.w;
            b.x += v1.x; b.y += v1.y; b.z += v1.z; b.w += v1.w;
        }
        if (i < eR) {
            int p0 = esort[i];
            float4 v0 = *(const float4*)(hin + (size_t)(p0 & 0xFFFF) * 64 + c * 4);
            a.x += v0.x; a.y += v0.y; a.z += v0.z; a.w += v0.w;
        }
        a.x += b.x; a.y += b.y; a.z += b.z; a.w += b.w;
        a.x += __shfl_xor(a.x, 16); a.y += __shfl_xor(a.y, 16);
        a.z += __shfl_xor(a.z, 16); a.w += __shfl_xor(a.w, 16);
        a.x += __shfl_xor(a.x, 32); a.y += __shfl_xor(a.y, 32);
        a.z += __shfl_xor(a.z, 32); a.w += __shfl_xor(a.w, 32);
        if (q == r) {
            float inv = 1.f / (float)max(eR - sR, 1);
            float4 m = {a.x * inv, a.y * inv, a.z * inv, a.w * inv};
            *(float4*)(means + (size_t)wid * 192 + r * 64 + c * 4) = m;
        }
    }
}

__global__ __launch_bounds__(256, 4) void fused_kernel(
    const int* __restrict__ x, const int* __restrict__ ei, const int* __restrict__ et,
    const int* __restrict__ batch, const float* __restrict__ emb,
    const float* __restrict__ w1rel, const float* __restrict__ w1root, const float* __restrict__ b1,
    const float* __restrict__ w2rel, const float* __restrict__ w2root, const float* __restrict__ b2,
    const float* __restrict__ linw, const float* __restrict__ linb, float* __restrict__ out,
    float* __restrict__ hA, float* __restrict__ hB, float* __restrict__ means,
    int* __restrict__ esort, int* __restrict__ rowstartR, int* __restrict__ bucket_start,
    int* __restrict__ totals, int* __restrict__ scratch,
    int* __restrict__ pcount, int* __restrict__ pre, int* barcnt,
    int N, int E, int G, int NBKT, int NCHK)
{
    __shared__ SMem sm;
    int t = threadIdx.x;
    int nblk = gridDim.x;
    int lane = t & 63;
    int embedBlocks = (N * 16 + 255) / 256;

    // ---- Phase A: embed + per-chunk bucket histograms ----
    for (int vb = blockIdx.x; vb < embedBlocks + NCHK; vb += nblk) {
        if (vb < embedBlocks) {
            int tt = vb * 256 + t;
            if (tt < N * 16) {
                int n = tt >> 4, q = tt & 15;
                int xv = x[n];
                float4 v = {0.f, 0.f, 0.f, 0.f};
                if (xv != 0) v = *(const float4*)(emb + (size_t)xv * 64 + q * 4);
                *(float4*)(hA + (size_t)n * 64 + q * 4) = v;
            }
        } else {
            int jb = vb - embedBlocks;
            int* cnt = sm.i;
            for (int b = t; b < 512; b += 256) cnt[b] = 0;
            __syncthreads();
            int base = jb * CHUNK;
#pragma unroll
            for (int i = 0; i < CHUNK / 256; ++i) {
                int e = base + i * 256 + t;
                if (e < E) atomicAdd(&cnt[ei[E + e] >> 7], 1);
            }
            __syncthreads();
            for (int b = t; b < NBKT; b += 256) pcount[jb * NBKT + b] = cnt[b];
            __syncthreads();
        }
    }
    grid_barrier(barcnt, 1, nblk);

    // ---- Phase B: per-bucket exclusive scan over chunk counts ----
    for (int b = blockIdx.x; b < NBKT; b += nblk) {
        int* ps = sm.i;
        if (b == 0 && t == 0) rowstartR[4 * N] = E;
        int v[4], s = 0;
#pragma unroll
        for (int i = 0; i < 4; ++i) {
            int jj = t * 4 + i;
            v[i] = (jj < NCHK) ? pcount[jj * NBKT + b] : 0;
            s += v[i];
        }
        ps[t] = s;
        __syncthreads();
        for (int o = 1; o < 256; o <<= 1) {
            int u = (t >= o) ? ps[t - o] : 0;
            __syncthreads();
            ps[t] += u;
            __syncthreads();
        }
        int run = (t > 0) ? ps[t - 1] : 0;
#pragma unroll
        for (int i = 0; i < 4; ++i) {
            int jj = t * 4 + i;
            if (jj < NCHK) pre[jj * NBKT + b] = run;
            run += v[i];
        }
        if (t == 255) totals[b] = run;
        __syncthreads();
    }
    grid_barrier(barcnt, 2, nblk);

    // ---- Phase C: scatter (deterministic bases, LDS fill atomics only) ----
    for (int j = blockIdx.x; j < NCHK; j += nblk) {
        int* bs = sm.i;
        int* fill2 = sm.i + 512;
        int* ps = sm.i + 1024;
        int a0 = (2 * t < NBKT) ? totals[2 * t] : 0;
        int a1 = (2 * t + 1 < NBKT) ? totals[2 * t + 1] : 0;
        ps[t] = a0 + a1;
        __syncthreads();
        for (int o = 1; o < 256; o <<= 1) {
            int u = (t >= o) ? ps[t - o] : 0;
            __syncthreads();
            ps[t] += u;
            __syncthreads();
        }
        int basex = (t > 0) ? ps[t - 1] : 0;
        bs[2 * t] = basex;
        bs[2 * t + 1] = basex + a0;
        fill2[t] = 0; fill2[t + 256] = 0;
        __syncthreads();
        if (j == 0) {
            for (int b = t; b < NBKT; b += 256) bucket_start[b] = bs[b];
            if (t == 0) bucket_start[NBKT] = E;
        }
        for (int b = t; b < NBKT; b += 256) bs[b] += pre[j * NBKT + b];
        __syncthreads();
        int base = j * CHUNK;
#pragma unroll
        for (int i = 0; i < CHUNK / 256; ++i) {
            int e = base + i * 256 + t;
            if (e < E) {
                int s = ei[e], d = ei[E + e], r = et[e];
                int b = d >> 7;
                int pos = bs[b] + atomicAdd(&fill2[b], 1);
                esort[pos] = s | (r << 16) | ((d & 127) << 18);
            }
        }
        __syncthreads();
    }
    grid_barrier(barcnt, 3, nblk);

    // ---- Phase D: per-bucket 512-bin counting sort -> rowstartR ----
    for (int b = blockIdx.x; b < NBKT; b += nblk) {
        int* cnt = sm.i;
        int* off = sm.i + 512;
        int* fill = sm.i + 1024;
        int* ps = sm.i + 1536;
        int s = bucket_start[b], e = bucket_start[b + 1];
        cnt[t] = 0; cnt[t + 256] = 0; fill[t] = 0; fill[t + 256] = 0;
        __syncthreads();
        int* scr = scratch + (size_t)b * 8192;
        for (int i = s + t; i < e; i += 256) {
            int p = esort[i];
            scr[i - s] = p;
            atomicAdd(&cnt[(p >> 16) & 0x1FF], 1);
        }
        __syncthreads();
        int a0 = cnt[2 * t], a1 = cnt[2 * t + 1];
        ps[t] = a0 + a1;
        __syncthreads();
        for (int o = 1; o < 256; o <<= 1) {
            int v = (t >= o) ? ps[t - o] : 0;
            __syncthreads();
            ps[t] += v;
            __syncthreads();
        }
        int basex = (t > 0) ? ps[t - 1] : 0;
        off[2 * t] = basex;
        off[2 * t + 1] = basex + a0;
        __syncthreads();
        int d0 = b * 128 + (2 * t >> 2);
        if (d0 < N) rowstartR[b * 512 + 2 * t] = s + off[2 * t];
        int d1 = b * 128 + ((2 * t + 1) >> 2);
        if (d1 < N) rowstartR[b * 512 + 2 * t + 1] = s + off[2 * t + 1];
        __syncthreads();
        for (int i = s + t; i < e; i += 256) {
            int p = scr[i - s];
            int bin = (p >> 16) & 0x1FF;
            int pos = s + off[bin] + atomicAdd(&fill[bin], 1);
            esort[pos] = p;
        }
        __syncthreads();
    }
    grid_barrier(barcnt, 4, nblk);

    int gwave = (blockIdx.x * 256 + t) >> 6;
    int totw = nblk * 4;
    int tfB = ((N + 3) / 4 * 16 + 255) / 256;

    // ---- Phase E: agg layer 1 (hA -> means) ----
    for (int wid = gwave; wid < N; wid += totw)
        agg_dst(wid, lane, hA, rowstartR, esort, means);
    grid_barrier(barcnt, 5, nblk);

    // ---- Phase F: transform layer 1 (hA, means -> hB) ----
    for (int vb = blockIdx.x; vb < tfB; vb += nblk)
        transform_vb(sm.w, vb, t, hA, means, w1root, w1rel, b1, hB, N);
    grid_barrier(barcnt, 6, nblk);

    // ---- Phase G: agg layer 2 (hB -> means) ----
    for (int wid = gwave; wid < N; wid += totw)
        agg_dst(wid, lane, hB, rowstartR, esort, means);
    grid_barrier(barcnt, 7, nblk);

    // ---- Phase H: transform layer 2 (hB, means -> hA) ----
    for (int vb = blockIdx.x; vb < tfB; vb += nblk)
        transform_vb(sm.w, vb, t, hB, means, w2root, w2rel, b2, hA, N);
    grid_barrier(barcnt, 8, nblk);

    // ---- Phase I: global mean pool + linear head ----
    for (int g = gwave; g < G; g += totw) {
        int lo = 0, hi = N;
        while (lo < hi) { int mid = (lo + hi) >> 1; if (batch[mid] < g) lo = mid + 1; else hi = mid; }
        int s = lo;
        lo = 0; hi = N;
        while (lo < hi) { int mid = (lo + hi) >> 1; if (batch[mid] < g + 1) lo = mid + 1; else hi = mid; }
        int e = lo;
        float sum = 0.f;
        for (int n = s; n < e; ++n) sum += hA[(size_t)n * 64 + lane];
        float mean = sum / (float)max(e - s, 1);
        float d0 = mean * linw[lane * 2 + 0];
        float d1 = mean * linw[lane * 2 + 1];
        for (int off = 32; off > 0; off >>= 1) {
            d0 += __shfl_down(d0, off);
            d1 += __shfl_down(d1, off);
        }
        if (lane == 0) {
            out[g * 2 + 0] = d0 + linb[0];
            out[g * 2 + 1] = d1 + linb[1];
        }
    }
}

extern "C" void kernel_launch(void* const* d_in, const int* in_sizes, int n_in,
                              void* d_out, int out_size, void* d_ws, size_t ws_size,
                              hipStream_t stream)
{
    const int*   x      = (const int*)d_in[0];
    const int*   ei     = (const int*)d_in[1];
    const int*   et     = (const int*)d_in[2];
    const int*   batch  = (const int*)d_in[3];
    const float* emb    = (const float*)d_in[4];
    const float* w1rel  = (const float*)d_in[5];
    const float* w1root = (const float*)d_in[6];
    const float* b1     = (const float*)d_in[7];
    const float* w2rel  = (const float*)d_in[8];
    const float* w2root = (const float*)d_in[9];
    const float* b2     = (const float*)d_in[10];
    const float* linw   = (const float*)d_in[11];
    const float* linb   = (const float*)d_in[12];
    float* out = (float*)d_out;

    int N = in_sizes[0];            // 50000
    int E = in_sizes[2];            // 1250000
    int G = out_size / 2;           // 512
    int NBKT = (N + 127) >> 7;      // 391
    int NCHK = (E + CHUNK - 1) / CHUNK;  // 611

    float* hA        = (float*)d_ws;                     // [N][64]
    float* hB        = hA + (size_t)N * 64;              // [N][64]
    float* means     = hB + (size_t)N * 64;              // [N][192]
    int*   esort     = (int*)(means + (size_t)N * 192);  // [E]
    int*   rowstartR = esort + E;                        // [4N+4]
    int*   bucket_start = rowstartR + 4 * N + 4;         // [NBKT+1]
    int*   totals    = bucket_start + NBKT + 1;          // [NBKT]
    int*   barcnt    = totals + NBKT;                    // [1]
    int*   scratch   = (int*)means;                      // sort scratch (12.8 MB)
    int*   pcount    = (int*)means + 4 * 1024 * 1024;    // [NCHK*NBKT]
    int*   pre       = (int*)means + 5 * 1024 * 1024;    // [NCHK*NBKT]

    hipMemsetAsync(barcnt, 0, sizeof(int), stream);

    void* args[] = {
        (void*)&x, (void*)&ei, (void*)&et, (void*)&batch, (void*)&emb,
        (void*)&w1rel, (void*)&w1root, (void*)&b1,
        (void*)&w2rel, (void*)&w2root, (void*)&b2,
        (void*)&linw, (void*)&linb, (void*)&out,
        (void*)&hA, (void*)&hB, (void*)&means,
        (void*)&esort, (void*)&rowstartR, (void*)&bucket_start,
        (void*)&totals, (void*)&scratch, (void*)&pcount, (void*)&pre, (void*)&barcnt,
        (void*)&N, (void*)&E, (void*)&G, (void*)&NBKT, (void*)&NCHK
    };
    hipLaunchKernel((void*)fused_kernel, dim3(1024), dim3(256), args, 0, stream);
}

// Round 14
// 339.051 us; speedup vs baseline: 6.3788x; 6.3788x over previous
//
#include <hip/hip_runtime.h>

#define CHUNK 2048

// Fused: embed blocks [0,embed_blocks) + per-chunk bucket histogram blocks.
__global__ __launch_bounds__(256) void embed_count_kernel(
    const int* __restrict__ x, const float* __restrict__ emb, float* __restrict__ h0,
    const int* __restrict__ ei, int* __restrict__ pcount,
    int n_nodes, int n_edges, int n_bkt, int embed_blocks)
{
    __shared__ int cnt[512];
    int t = threadIdx.x;
    if ((int)blockIdx.x < embed_blocks) {
        int tt = blockIdx.x * 256 + t;
        if (tt < n_nodes * 16) {
            int n = tt >> 4, q = tt & 15;
            int xv = x[n];
            float4 v = {0.f, 0.f, 0.f, 0.f};
            if (xv != 0) v = *(const float4*)(emb + (size_t)xv * 64 + q * 4);
            *(float4*)(h0 + (size_t)n * 64 + q * 4) = v;
        }
        return;
    }
    int jb = blockIdx.x - embed_blocks;
    for (int b = t; b < 512; b += 256) cnt[b] = 0;
    __syncthreads();
    int base = jb * CHUNK;
#pragma unroll
    for (int i = 0; i < CHUNK / 256; ++i) {
        int e = base + i * 256 + t;
        if (e < n_edges) atomicAdd(&cnt[ei[n_edges + e] >> 7], 1);
    }
    __syncthreads();
    for (int b = t; b < n_bkt; b += 256) pcount[jb * n_bkt + b] = cnt[b];
}

// one block per bucket: exclusive scan over chunk counts -> pre, totals
__global__ __launch_bounds__(256) void colscan_kernel(
    const int* __restrict__ pcount, int* __restrict__ pre,
    int* __restrict__ totals, int* __restrict__ rowstartR,
    int n_chk, int n_bkt, int n_edges, int n_nodes)
{
    __shared__ int ps[256];
    int b = blockIdx.x, t = threadIdx.x;
    if (b == 0 && t == 0) rowstartR[4 * n_nodes] = n_edges;
    int v[4], s = 0;
#pragma unroll
    for (int i = 0; i < 4; ++i) {
        int jj = t * 4 + i;
        v[i] = (jj < n_chk) ? pcount[jj * n_bkt + b] : 0;
        s += v[i];
    }
    ps[t] = s;
    __syncthreads();
    for (int o = 1; o < 256; o <<= 1) {
        int u = (t >= o) ? ps[t - o] : 0;
        __syncthreads();
        ps[t] += u;
        __syncthreads();
    }
    int run = (t > 0) ? ps[t - 1] : 0;
#pragma unroll
    for (int i = 0; i < 4; ++i) {
        int jj = t * 4 + i;
        if (jj < n_chk) pre[jj * n_bkt + b] = run;
        run += v[i];
    }
    if (t == 255) totals[b] = run;
}

// 611 blocks x 2048 edges; deterministic bases (local scan of totals + pre row),
// LDS fill atomics only. Block 0 publishes bucket_start for the sort.
__global__ __launch_bounds__(256) void scatter_kernel(
    const int* __restrict__ ei, const int* __restrict__ et,
    const int* __restrict__ pre, const int* __restrict__ totals,
    int* __restrict__ esort, int* __restrict__ bucket_start,
    int n_edges, int n_bkt)
{
    __shared__ int bs[512], fill2[512], ps[256];
    int t = threadIdx.x, j = blockIdx.x;
    int a0 = (2 * t < n_bkt) ? totals[2 * t] : 0;
    int a1 = (2 * t + 1 < n_bkt) ? totals[2 * t + 1] : 0;
    ps[t] = a0 + a1;
    __syncthreads();
    for (int o = 1; o < 256; o <<= 1) {
        int u = (t >= o) ? ps[t - o] : 0;
        __syncthreads();
        ps[t] += u;
        __syncthreads();
    }
    int basex = (t > 0) ? ps[t - 1] : 0;
    bs[2 * t] = basex;
    bs[2 * t + 1] = basex + a0;
    fill2[t] = 0; fill2[t + 256] = 0;
    __syncthreads();
    if (j == 0) {
        for (int b = t; b < n_bkt; b += 256) bucket_start[b] = bs[b];
        if (t == 0) bucket_start[n_bkt] = n_edges;
    }
    for (int b = t; b < n_bkt; b += 256) bs[b] += pre[j * n_bkt + b];
    __syncthreads();
    int base = j * CHUNK;
#pragma unroll
    for (int i = 0; i < CHUNK / 256; ++i) {
        int e = base + i * 256 + t;
        if (e < n_edges) {
            int s = ei[e], d = ei[n_edges + e], r = et[e];
            int b = d >> 7;
            int pos = bs[b] + atomicAdd(&fill2[b], 1);
            esort[pos] = s | (r << 16) | ((d & 127) << 18);
        }
    }
}

// one block per bucket: 512-bin counting sort (bin = dstlo*4 + r),
// emits rowstartR[dst*4 + r].
__global__ __launch_bounds__(256) void bucket_sort_kernel(
    const int* __restrict__ bucket_start, int* __restrict__ esort,
    int* __restrict__ scratch, int* __restrict__ rowstartR, int n_nodes)
{
    __shared__ int cnt[512], off[512], fill[512], ps[256];
    int t = threadIdx.x, b = blockIdx.x;
    int s = bucket_start[b], e = bucket_start[b + 1];
    cnt[t] = 0; cnt[t + 256] = 0; fill[t] = 0; fill[t + 256] = 0;
    __syncthreads();
    int* scr = scratch + (size_t)b * 8192;
    for (int i = s + t; i < e; i += 256) {
        int p = esort[i];
        scr[i - s] = p;
        atomicAdd(&cnt[(p >> 16) & 0x1FF], 1);
    }
    __syncthreads();
    int a0 = cnt[2 * t], a1 = cnt[2 * t + 1];
    ps[t] = a0 + a1;
    __syncthreads();
    for (int o = 1; o < 256; o <<= 1) {
        int v = (t >= o) ? ps[t - o] : 0;
        __syncthreads();
        ps[t] += v;
        __syncthreads();
    }
    int basex = (t > 0) ? ps[t - 1] : 0;
    off[2 * t] = basex;
    off[2 * t + 1] = basex + a0;
    __syncthreads();
    int d0 = b * 128 + (2 * t >> 2);
    if (d0 < n_nodes) rowstartR[b * 512 + 2 * t] = s + off[2 * t];
    int d1 = b * 128 + ((2 * t + 1) >> 2);
    if (d1 < n_nodes) rowstartR[b * 512 + 2 * t + 1] = s + off[2 * t + 1];
    __syncthreads();
    for (int i = s + t; i < e; i += 256) {
        int p = scr[i - s];
        int bin = (p >> 16) & 0x1FF;
        int pos = s + off[bin] + atomicAdd(&fill[bin], 1);
        esort[pos] = p;
    }
}

// one wave per dst. Masked full-row MLP: quarter q takes a 4-edge window per
// 16-stride over the WHOLE row (balanced: row ~25 edges vs rel-subrange ~8),
// 4 independent row-loads in flight; relation routing via payload r-bits with
// predicated FMAs into 3 accumulators. Counts free from rowstartR widths.
__global__ __launch_bounds__(256) void agg_kernel(
    const float* __restrict__ hin, const int* __restrict__ rowstartR,
    const int* __restrict__ esort, float* __restrict__ means, int n_nodes)
{
    int wid = (blockIdx.x * 256 + threadIdx.x) >> 6;
    int lane = threadIdx.x & 63;
    if (wid >= n_nodes) return;
    int q = lane >> 4;
    int c = lane & 15;
    int4 rs = *(const int4*)(rowstartR + wid * 4);
    int s = rs.x, e = rs.w;

    float4 a0 = {0.f,0.f,0.f,0.f}, a1 = {0.f,0.f,0.f,0.f}, a2 = {0.f,0.f,0.f,0.f};

    int i = s + 4 * q;
    for (; i + 4 <= e; i += 16) {
        int p0 = esort[i], p1 = esort[i + 1], p2 = esort[i + 2], p3 = esort[i + 3];
        float4 v0 = *(const float4*)(hin + (size_t)(p0 & 0xFFFF) * 64 + c * 4);
        float4 v1 = *(const float4*)(hin + (size_t)(p1 & 0xFFFF) * 64 + c * 4);
        float4 v2 = *(const float4*)(hin + (size_t)(p2 & 0xFFFF) * 64 + c * 4);
        float4 v3 = *(const float4*)(hin + (size_t)(p3 & 0xFFFF) * 64 + c * 4);
#pragma unroll
        for (int m = 0; m < 4; ++m) {
            int p = m == 0 ? p0 : m == 1 ? p1 : m == 2 ? p2 : p3;
            float4 v = m == 0 ? v0 : m == 1 ? v1 : m == 2 ? v2 : v3;
            int r = (p >> 16) & 3;
            float m0 = (r == 0) ? 1.f : 0.f;
            float m1 = (r == 1) ? 1.f : 0.f;
            float m2 = (r == 2) ? 1.f : 0.f;
            a0.x = fmaf(m0, v.x, a0.x); a0.y = fmaf(m0, v.y, a0.y);
            a0.z = fmaf(m0, v.z, a0.z); a0.w = fmaf(m0, v.w, a0.w);
            a1.x = fmaf(m1, v.x, a1.x); a1.y = fmaf(m1, v.y, a1.y);
            a1.z = fmaf(m1, v.z, a1.z); a1.w = fmaf(m1, v.w, a1.w);
            a2.x = fmaf(m2, v.x, a2.x); a2.y = fmaf(m2, v.y, a2.y);
            a2.z = fmaf(m2, v.z, a2.z); a2.w = fmaf(m2, v.w, a2.w);
        }
    }
#pragma unroll
    for (int m = 0; m < 3; ++m) {   // partial window tail (e - i <= 3)
        int ii = i + m;
        if (ii < e) {
            int p = esort[ii];
            float4 v = *(const float4*)(hin + (size_t)(p & 0xFFFF) * 64 + c * 4);
            int r = (p >> 16) & 3;
            float m0 = (r == 0) ? 1.f : 0.f;
            float m1 = (r == 1) ? 1.f : 0.f;
            float m2 = (r == 2) ? 1.f : 0.f;
            a0.x = fmaf(m0, v.x, a0.x); a0.y = fmaf(m0, v.y, a0.y);
            a0.z = fmaf(m0, v.z, a0.z); a0.w = fmaf(m0, v.w, a0.w);
            a1.x = fmaf(m1, v.x, a1.x); a1.y = fmaf(m1, v.y, a1.y);
            a1.z = fmaf(m1, v.z, a1.z); a1.w = fmaf(m1, v.w, a1.w);
            a2.x = fmaf(m2, v.x, a2.x); a2.y = fmaf(m2, v.y, a2.y);
            a2.z = fmaf(m2, v.z, a2.z); a2.w = fmaf(m2, v.w, a2.w);
        }
    }
#pragma unroll
    for (int off = 16; off < 64; off <<= 1) {
        a0.x += __shfl_xor(a0.x, off); a0.y += __shfl_xor(a0.y, off);
        a0.z += __shfl_xor(a0.z, off); a0.w += __shfl_xor(a0.w, off);
        a1.x += __shfl_xor(a1.x, off); a1.y += __shfl_xor(a1.y, off);
        a1.z += __shfl_xor(a1.z, off); a1.w += __shfl_xor(a1.w, off);
        a2.x += __shfl_xor(a2.x, off); a2.y += __shfl_xor(a2.y, off);
        a2.z += __shfl_xor(a2.z, off); a2.w += __shfl_xor(a2.w, off);
    }
    if (q < 3) {
        int cnt = (q == 0) ? (rs.y - rs.x) : (q == 1) ? (rs.z - rs.y) : (rs.w - rs.z);
        float4 a = (q == 0) ? a0 : (q == 1) ? a1 : a2;
        float inv = 1.f / (float)max(cnt, 1);
        float4 m = {a.x * inv, a.y * inv, a.z * inv, a.w * inv};
        *(float4*)(means + (size_t)wid * 192 + q * 64 + c * 4) = m;
    }
}

// thread = (4-node group, j-quad). W streamed through LDS in 4 slabs of 64
// rows (16 KB), double-buffered (32 KB -> 5 blocks/CU).
__global__ __launch_bounds__(256) void transform_kernel(
    const float* __restrict__ hin, const float* __restrict__ means,
    const float* __restrict__ wroot, const float* __restrict__ wrel,
    const float* __restrict__ bias, float* __restrict__ hout, int n_nodes)
{
    __shared__ float wsh[2][4096];   // 2 x 16 KB
    int t = threadIdx.x;
    int gt = blockIdx.x * 256 + t;
    int g = gt >> 4, q = gt & 15;
    int n0 = g * 4;
    bool active = (n0 < n_nodes);

    {
        const float4* sp = (const float4*)wroot;
        float4* d = (float4*)wsh[0];
#pragma unroll
        for (int i = 0; i < 4; ++i) d[t + i * 256] = sp[t + i * 256];
    }

    float4 acc[4];
    float4 b = {0.f, 0.f, 0.f, 0.f};
    if (active) b = *(const float4*)(bias + q * 4);
#pragma unroll
    for (int i = 0; i < 4; ++i) acc[i] = b;

    const float* hv = hin + (size_t)n0 * 64;
    const float* mv = means + (size_t)n0 * 192;

    for (int s = 0; s < 4; ++s) {
        __syncthreads();
        if (s < 3) {
            const float4* sp = (const float4*)wrel + (size_t)s * 1024;
            float4* d = (float4*)wsh[(s + 1) & 1];
#pragma unroll
            for (int i = 0; i < 4; ++i) d[t + i * 256] = sp[t + i * 256];
        }
        const float* vbase = (s == 0) ? hv : (mv + (s - 1) * 64);
        int vstride = (s == 0) ? 64 : 192;
        const float* wbuf = wsh[s & 1];
        if (active) {
#pragma unroll 4
            for (int k4 = 0; k4 < 16; ++k4) {
                float4 v[4];
#pragma unroll
                for (int i = 0; i < 4; ++i)
                    v[i] = *(const float4*)(vbase + i * vstride + k4 * 4);
#pragma unroll
                for (int kk = 0; kk < 4; ++kk) {
                    float4 w = *(const float4*)(wbuf + (k4 * 4 + kk) * 64 + q * 4);
#pragma unroll
                    for (int i = 0; i < 4; ++i) {
                        float sv = kk == 0 ? v[i].x : kk == 1 ? v[i].y : kk == 2 ? v[i].z : v[i].w;
                        acc[i].x = fmaf(sv, w.x, acc[i].x);
                        acc[i].y = fmaf(sv, w.y, acc[i].y);
                        acc[i].z = fmaf(sv, w.z, acc[i].z);
                        acc[i].w = fmaf(sv, w.w, acc[i].w);
                    }
                }
            }
        }
    }
    if (active) {
        float* o = hout + (size_t)n0 * 64 + q * 4;
#pragma unroll
        for (int i = 0; i < 4; ++i) {
            float4 r = {fmaxf(acc[i].x, 0.f), fmaxf(acc[i].y, 0.f),
                        fmaxf(acc[i].z, 0.f), fmaxf(acc[i].w, 0.f)};
            *(float4*)(o + i * 64) = r;
        }
    }
}

// wave per graph: batch sorted -> binary-search bounds, mean, then 64->2 head
__global__ __launch_bounds__(256) void pool_kernel(
    const float* __restrict__ h2, const int* __restrict__ batch,
    const float* __restrict__ linw, const float* __restrict__ linb,
    float* __restrict__ out, int n_nodes, int n_graphs)
{
    int wid = (blockIdx.x * 256 + threadIdx.x) >> 6;
    int lane = threadIdx.x & 63;
    if (wid >= n_graphs) return;
    int g = wid;
    int lo = 0, hi = n_nodes;
    while (lo < hi) { int mid = (lo + hi) >> 1; if (batch[mid] < g) lo = mid + 1; else hi = mid; }
    int s = lo;
    lo = 0; hi = n_nodes;
    while (lo < hi) { int mid = (lo + hi) >> 1; if (batch[mid] < g + 1) lo = mid + 1; else hi = mid; }
    int e = lo;
    float sum = 0.f;
    for (int n = s; n < e; ++n) sum += h2[(size_t)n * 64 + lane];
    float mean = sum / (float)max(e - s, 1);
    float d0 = mean * linw[lane * 2 + 0];
    float d1 = mean * linw[lane * 2 + 1];
    for (int off = 32; off > 0; off >>= 1) {
        d0 += __shfl_down(d0, off);
        d1 += __shfl_down(d1, off);
    }
    if (lane == 0) {
        out[g * 2 + 0] = d0 + linb[0];
        out[g * 2 + 1] = d1 + linb[1];
    }
}

extern "C" void kernel_launch(void* const* d_in, const int* in_sizes, int n_in,
                              void* d_out, int out_size, void* d_ws, size_t ws_size,
                              hipStream_t stream)
{
    const int*   x      = (const int*)d_in[0];
    const int*   ei     = (const int*)d_in[1];
    const int*   et     = (const int*)d_in[2];
    const int*   batch  = (const int*)d_in[3];
    const float* emb    = (const float*)d_in[4];
    const float* w1rel  = (const float*)d_in[5];
    const float* w1root = (const float*)d_in[6];
    const float* b1     = (const float*)d_in[7];
    const float* w2rel  = (const float*)d_in[8];
    const float* w2root = (const float*)d_in[9];
    const float* b2     = (const float*)d_in[10];
    const float* linw   = (const float*)d_in[11];
    const float* linb   = (const float*)d_in[12];
    float* out = (float*)d_out;

    const int N = in_sizes[0];            // 50000
    const int E = in_sizes[2];            // 1250000
    const int G = out_size / 2;           // 512
    const int NBKT = (N + 127) >> 7;      // 391
    const int NCHK = (E + CHUNK - 1) / CHUNK;  // 611

    float* hA        = (float*)d_ws;                     // [N][64]
    float* hB        = hA + (size_t)N * 64;              // [N][64]
    float* means     = hB + (size_t)N * 64;              // [N][192]
    int*   esort     = (int*)(means + (size_t)N * 192);  // [E]
    int*   rowstartR = esort + E;                        // [4N+4]
    int*   bucket_start = rowstartR + 4 * N + 4;         // [NBKT+1]
    int*   totals    = bucket_start + NBKT + 1;          // [NBKT]
    int*   scratch   = (int*)means;                      // sort scratch (12.8 MB)
    int*   pcount    = (int*)means + 4 * 1024 * 1024;    // [NCHK*NBKT]
    int*   pre       = (int*)means + 5 * 1024 * 1024;    // [NCHK*NBKT]

    int embedBlocks = (N * 16 + 255) / 256;              // 3125
    embed_count_kernel<<<embedBlocks + NCHK, 256, 0, stream>>>(
        x, emb, hA, ei, pcount, N, E, NBKT, embedBlocks);
    colscan_kernel<<<NBKT, 256, 0, stream>>>(pcount, pre, totals, rowstartR, NCHK, NBKT, E, N);
    scatter_kernel<<<NCHK, 256, 0, stream>>>(ei, et, pre, totals, esort, bucket_start, E, NBKT);
    bucket_sort_kernel<<<NBKT, 256, 0, stream>>>(bucket_start, esort, scratch, rowstartR, N);

    int aggBlocks = (N * 64 + 255) / 256;                // one wave per dst
    int tfBlocks  = ((N + 3) / 4 * 16 + 255) / 256;      // 4 nodes per thread
    agg_kernel<<<aggBlocks, 256, 0, stream>>>(hA, rowstartR, esort, means, N);
    transform_kernel<<<tfBlocks, 256, 0, stream>>>(hA, means, w1root, w1rel, b1, hB, N);
    agg_kernel<<<aggBlocks, 256, 0, stream>>>(hB, rowstartR, esort, means, N);
    transform_kernel<<<tfBlocks, 256, 0, stream>>>(hB, means, w2root, w2rel, b2, hA, N);

    pool_kernel<<<(G * 64 + 255) / 256, 256, 0, stream>>>(hA, batch, linw, linb, out, N, G);
}

// Round 15
// 312.364 us; speedup vs baseline: 6.9238x; 1.0854x over previous
//
#include <hip/hip_runtime.h>

#define CHUNK 2048

// Fused: embed blocks [0,embed_blocks) + per-chunk bucket histogram blocks.
__global__ __launch_bounds__(256) void embed_count_kernel(
    const int* __restrict__ x, const float* __restrict__ emb, float* __restrict__ h0,
    const int* __restrict__ ei, int* __restrict__ pcount,
    int n_nodes, int n_edges, int n_bkt, int embed_blocks)
{
    __shared__ int cnt[512];
    int t = threadIdx.x;
    if ((int)blockIdx.x < embed_blocks) {
        int tt = blockIdx.x * 256 + t;
        if (tt < n_nodes * 16) {
            int n = tt >> 4, q = tt & 15;
            int xv = x[n];
            float4 v = {0.f, 0.f, 0.f, 0.f};
            if (xv != 0) v = *(const float4*)(emb + (size_t)xv * 64 + q * 4);
            *(float4*)(h0 + (size_t)n * 64 + q * 4) = v;
        }
        return;
    }
    int jb = blockIdx.x - embed_blocks;
    for (int b = t; b < 512; b += 256) cnt[b] = 0;
    __syncthreads();
    int base = jb * CHUNK;
#pragma unroll
    for (int i = 0; i < CHUNK / 256; ++i) {
        int e = base + i * 256 + t;
        if (e < n_edges) atomicAdd(&cnt[ei[n_edges + e] >> 7], 1);
    }
    __syncthreads();
    for (int b = t; b < n_bkt; b += 256) pcount[jb * n_bkt + b] = cnt[b];
}

// one block per bucket: exclusive scan over chunk counts -> pre, totals
__global__ __launch_bounds__(256) void colscan_kernel(
    const int* __restrict__ pcount, int* __restrict__ pre,
    int* __restrict__ totals, int* __restrict__ rowstartR,
    int n_chk, int n_bkt, int n_edges, int n_nodes)
{
    __shared__ int ps[256];
    int b = blockIdx.x, t = threadIdx.x;
    if (b == 0 && t == 0) rowstartR[4 * n_nodes] = n_edges;
    int v[4], s = 0;
#pragma unroll
    for (int i = 0; i < 4; ++i) {
        int jj = t * 4 + i;
        v[i] = (jj < n_chk) ? pcount[jj * n_bkt + b] : 0;
        s += v[i];
    }
    ps[t] = s;
    __syncthreads();
    for (int o = 1; o < 256; o <<= 1) {
        int u = (t >= o) ? ps[t - o] : 0;
        __syncthreads();
        ps[t] += u;
        __syncthreads();
    }
    int run = (t > 0) ? ps[t - 1] : 0;
#pragma unroll
    for (int i = 0; i < 4; ++i) {
        int jj = t * 4 + i;
        if (jj < n_chk) pre[jj * n_bkt + b] = run;
        run += v[i];
    }
    if (t == 255) totals[b] = run;
}

// 611 blocks x 2048 edges; deterministic bases (local scan of totals + pre row),
// LDS fill atomics only. Block 0 publishes bucket_start for the sort.
__global__ __launch_bounds__(256) void scatter_kernel(
    const int* __restrict__ ei, const int* __restrict__ et,
    const int* __restrict__ pre, const int* __restrict__ totals,
    int* __restrict__ esort, int* __restrict__ bucket_start,
    int n_edges, int n_bkt)
{
    __shared__ int bs[512], fill2[512], ps[256];
    int t = threadIdx.x, j = blockIdx.x;
    int a0 = (2 * t < n_bkt) ? totals[2 * t] : 0;
    int a1 = (2 * t + 1 < n_bkt) ? totals[2 * t + 1] : 0;
    ps[t] = a0 + a1;
    __syncthreads();
    for (int o = 1; o < 256; o <<= 1) {
        int u = (t >= o) ? ps[t - o] : 0;
        __syncthreads();
        ps[t] += u;
        __syncthreads();
    }
    int basex = (t > 0) ? ps[t - 1] : 0;
    bs[2 * t] = basex;
    bs[2 * t + 1] = basex + a0;
    fill2[t] = 0; fill2[t + 256] = 0;
    __syncthreads();
    if (j == 0) {
        for (int b = t; b < n_bkt; b += 256) bucket_start[b] = bs[b];
        if (t == 0) bucket_start[n_bkt] = n_edges;
    }
    for (int b = t; b < n_bkt; b += 256) bs[b] += pre[j * n_bkt + b];
    __syncthreads();
    int base = j * CHUNK;
#pragma unroll
    for (int i = 0; i < CHUNK / 256; ++i) {
        int e = base + i * 256 + t;
        if (e < n_edges) {
            int s = ei[e], d = ei[n_edges + e], r = et[e];
            int b = d >> 7;
            int pos = bs[b] + atomicAdd(&fill2[b], 1);
            esort[pos] = s | (r << 16) | ((d & 127) << 18);
        }
    }
}

// one block per bucket: 512-bin counting sort (bin = dstlo*4 + r),
// emits rowstartR[dst*4 + r].
__global__ __launch_bounds__(256) void bucket_sort_kernel(
    const int* __restrict__ bucket_start, int* __restrict__ esort,
    int* __restrict__ scratch, int* __restrict__ rowstartR, int n_nodes)
{
    __shared__ int cnt[512], off[512], fill[512], ps[256];
    int t = threadIdx.x, b = blockIdx.x;
    int s = bucket_start[b], e = bucket_start[b + 1];
    cnt[t] = 0; cnt[t + 256] = 0; fill[t] = 0; fill[t + 256] = 0;
    __syncthreads();
    int* scr = scratch + (size_t)b * 8192;
    for (int i = s + t; i < e; i += 256) {
        int p = esort[i];
        scr[i - s] = p;
        atomicAdd(&cnt[(p >> 16) & 0x1FF], 1);
    }
    __syncthreads();
    int a0 = cnt[2 * t], a1 = cnt[2 * t + 1];
    ps[t] = a0 + a1;
    __syncthreads();
    for (int o = 1; o < 256; o <<= 1) {
        int v = (t >= o) ? ps[t - o] : 0;
        __syncthreads();
        ps[t] += v;
        __syncthreads();
    }
    int basex = (t > 0) ? ps[t - 1] : 0;
    off[2 * t] = basex;
    off[2 * t + 1] = basex + a0;
    __syncthreads();
    int d0 = b * 128 + (2 * t >> 2);
    if (d0 < n_nodes) rowstartR[b * 512 + 2 * t] = s + off[2 * t];
    int d1 = b * 128 + ((2 * t + 1) >> 2);
    if (d1 < n_nodes) rowstartR[b * 512 + 2 * t + 1] = s + off[2 * t + 1];
    __syncthreads();
    for (int i = s + t; i < e; i += 256) {
        int p = scr[i - s];
        int bin = (p >> 16) & 0x1FF;
        int pos = s + off[bin] + atomicAdd(&fill[bin], 1);
        esort[pos] = p;
    }
}

// one wave per dst. Masked full-row MLP: quarter q takes a 4-edge window per
// 16-stride over the whole row; 4 independent row-loads in flight; relation
// routing via payload r-bits with predicated FMAs. Counts free from rowstartR.
__global__ __launch_bounds__(256) void agg_kernel(
    const float* __restrict__ hin, const int* __restrict__ rowstartR,
    const int* __restrict__ esort, float* __restrict__ means, int n_nodes)
{
    int wid = (blockIdx.x * 256 + threadIdx.x) >> 6;
    int lane = threadIdx.x & 63;
    if (wid >= n_nodes) return;
    int q = lane >> 4;
    int c = lane & 15;
    int4 rs = *(const int4*)(rowstartR + wid * 4);
    int s = rs.x, e = rs.w;

    float4 a0 = {0.f,0.f,0.f,0.f}, a1 = {0.f,0.f,0.f,0.f}, a2 = {0.f,0.f,0.f,0.f};

    int i = s + 4 * q;
    for (; i + 4 <= e; i += 16) {
        int p0 = esort[i], p1 = esort[i + 1], p2 = esort[i + 2], p3 = esort[i + 3];
        float4 v0 = *(const float4*)(hin + (size_t)(p0 & 0xFFFF) * 64 + c * 4);
        float4 v1 = *(const float4*)(hin + (size_t)(p1 & 0xFFFF) * 64 + c * 4);
        float4 v2 = *(const float4*)(hin + (size_t)(p2 & 0xFFFF) * 64 + c * 4);
        float4 v3 = *(const float4*)(hin + (size_t)(p3 & 0xFFFF) * 64 + c * 4);
#pragma unroll
        for (int m = 0; m < 4; ++m) {
            int p = m == 0 ? p0 : m == 1 ? p1 : m == 2 ? p2 : p3;
            float4 v = m == 0 ? v0 : m == 1 ? v1 : m == 2 ? v2 : v3;
            int r = (p >> 16) & 3;
            float m0 = (r == 0) ? 1.f : 0.f;
            float m1 = (r == 1) ? 1.f : 0.f;
            float m2 = (r == 2) ? 1.f : 0.f;
            a0.x = fmaf(m0, v.x, a0.x); a0.y = fmaf(m0, v.y, a0.y);
            a0.z = fmaf(m0, v.z, a0.z); a0.w = fmaf(m0, v.w, a0.w);
            a1.x = fmaf(m1, v.x, a1.x); a1.y = fmaf(m1, v.y, a1.y);
            a1.z = fmaf(m1, v.z, a1.z); a1.w = fmaf(m1, v.w, a1.w);
            a2.x = fmaf(m2, v.x, a2.x); a2.y = fmaf(m2, v.y, a2.y);
            a2.z = fmaf(m2, v.z, a2.z); a2.w = fmaf(m2, v.w, a2.w);
        }
    }
#pragma unroll
    for (int m = 0; m < 3; ++m) {   // partial window tail (e - i <= 3)
        int ii = i + m;
        if (ii < e) {
            int p = esort[ii];
            float4 v = *(const float4*)(hin + (size_t)(p & 0xFFFF) * 64 + c * 4);
            int r = (p >> 16) & 3;
            float m0 = (r == 0) ? 1.f : 0.f;
            float m1 = (r == 1) ? 1.f : 0.f;
            float m2 = (r == 2) ? 1.f : 0.f;
            a0.x = fmaf(m0, v.x, a0.x); a0.y = fmaf(m0, v.y, a0.y);
            a0.z = fmaf(m0, v.z, a0.z); a0.w = fmaf(m0, v.w, a0.w);
            a1.x = fmaf(m1, v.x, a1.x); a1.y = fmaf(m1, v.y, a1.y);
            a1.z = fmaf(m1, v.z, a1.z); a1.w = fmaf(m1, v.w, a1.w);
            a2.x = fmaf(m2, v.x, a2.x); a2.y = fmaf(m2, v.y, a2.y);
            a2.z = fmaf(m2, v.z, a2.z); a2.w = fmaf(m2, v.w, a2.w);
        }
    }
#pragma unroll
    for (int off = 16; off < 64; off <<= 1) {
        a0.x += __shfl_xor(a0.x, off); a0.y += __shfl_xor(a0.y, off);
        a0.z += __shfl_xor(a0.z, off); a0.w += __shfl_xor(a0.w, off);
        a1.x += __shfl_xor(a1.x, off); a1.y += __shfl_xor(a1.y, off);
        a1.z += __shfl_xor(a1.z, off); a1.w += __shfl_xor(a1.w, off);
        a2.x += __shfl_xor(a2.x, off); a2.y += __shfl_xor(a2.y, off);
        a2.z += __shfl_xor(a2.z, off); a2.w += __shfl_xor(a2.w, off);
    }
    if (q < 3) {
        int cnt = (q == 0) ? (rs.y - rs.x) : (q == 1) ? (rs.z - rs.y) : (rs.w - rs.z);
        float4 a = (q == 0) ? a0 : (q == 1) ? a1 : a2;
        float inv = 1.f / (float)max(cnt, 1);
        float4 m = {a.x * inv, a.y * inv, a.z * inv, a.w * inv};
        *(float4*)(means + (size_t)wid * 192 + q * 64 + c * 4) = m;
    }
}

// thread = (4-node group, j-quad). W streamed through LDS in 4 slabs of 64
// rows (16 KB), double-buffered (32 KB -> 5 blocks/CU).
__global__ __launch_bounds__(256) void transform_kernel(
    const float* __restrict__ hin, const float* __restrict__ means,
    const float* __restrict__ wroot, const float* __restrict__ wrel,
    const float* __restrict__ bias, float* __restrict__ hout, int n_nodes)
{
    __shared__ float wsh[2][4096];   // 2 x 16 KB
    int t = threadIdx.x;
    int gt = blockIdx.x * 256 + t;
    int g = gt >> 4, q = gt & 15;
    int n0 = g * 4;
    bool active = (n0 < n_nodes);

    {
        const float4* sp = (const float4*)wroot;
        float4* d = (float4*)wsh[0];
#pragma unroll
        for (int i = 0; i < 4; ++i) d[t + i * 256] = sp[t + i * 256];
    }

    float4 acc[4];
    float4 b = {0.f, 0.f, 0.f, 0.f};
    if (active) b = *(const float4*)(bias + q * 4);
#pragma unroll
    for (int i = 0; i < 4; ++i) acc[i] = b;

    const float* hv = hin + (size_t)n0 * 64;
    const float* mv = means + (size_t)n0 * 192;

    for (int s = 0; s < 4; ++s) {
        __syncthreads();
        if (s < 3) {
            const float4* sp = (const float4*)wrel + (size_t)s * 1024;
            float4* d = (float4*)wsh[(s + 1) & 1];
#pragma unroll
            for (int i = 0; i < 4; ++i) d[t + i * 256] = sp[t + i * 256];
        }
        const float* vbase = (s == 0) ? hv : (mv + (s - 1) * 64);
        int vstride = (s == 0) ? 64 : 192;
        const float* wbuf = wsh[s & 1];
        if (active) {
#pragma unroll 4
            for (int k4 = 0; k4 < 16; ++k4) {
                float4 v[4];
#pragma unroll
                for (int i = 0; i < 4; ++i)
                    v[i] = *(const float4*)(vbase + i * vstride + k4 * 4);
#pragma unroll
                for (int kk = 0; kk < 4; ++kk) {
                    float4 w = *(const float4*)(wbuf + (k4 * 4 + kk) * 64 + q * 4);
#pragma unroll
                    for (int i = 0; i < 4; ++i) {
                        float sv = kk == 0 ? v[i].x : kk == 1 ? v[i].y : kk == 2 ? v[i].z : v[i].w;
                        acc[i].x = fmaf(sv, w.x, acc[i].x);
                        acc[i].y = fmaf(sv, w.y, acc[i].y);
                        acc[i].z = fmaf(sv, w.z, acc[i].z);
                        acc[i].w = fmaf(sv, w.w, acc[i].w);
                    }
                }
            }
        }
    }
    if (active) {
        float* o = hout + (size_t)n0 * 64 + q * 4;
#pragma unroll
        for (int i = 0; i < 4; ++i) {
            float4 r = {fmaxf(acc[i].x, 0.f), fmaxf(acc[i].y, 0.f),
                        fmaxf(acc[i].z, 0.f), fmaxf(acc[i].w, 0.f)};
            *(float4*)(o + i * 64) = r;
        }
    }
}

// BLOCK per graph (512 blocks): wave w sums nodes s+w, s+w+4, ... (coalesced
// 256 B rows, L2/L3-resident), LDS-reduce the 4 partial channel vectors,
// wave 0 runs the 64->2 head. Replaces the 8-block serial version (44 us,
// occupancy 4% -> pure parallelism bug).
__global__ __launch_bounds__(256) void pool_kernel(
    const float* __restrict__ h2, const int* __restrict__ batch,
    const float* __restrict__ linw, const float* __restrict__ linb,
    float* __restrict__ out, int n_nodes, int n_graphs)
{
    __shared__ float red[4][64];
    int g = blockIdx.x;
    if (g >= n_graphs) return;
    int w = threadIdx.x >> 6;
    int lane = threadIdx.x & 63;

    int lo = 0, hi = n_nodes;
    while (lo < hi) { int mid = (lo + hi) >> 1; if (batch[mid] < g) lo = mid + 1; else hi = mid; }
    int s = lo;
    lo = 0; hi = n_nodes;
    while (lo < hi) { int mid = (lo + hi) >> 1; if (batch[mid] < g + 1) lo = mid + 1; else hi = mid; }
    int e = lo;

    float sum = 0.f;
    for (int n = s + w; n < e; n += 4) sum += h2[(size_t)n * 64 + lane];
    red[w][lane] = sum;
    __syncthreads();
    if (w == 0) {
        float total = red[0][lane] + red[1][lane] + red[2][lane] + red[3][lane];
        float mean = total / (float)max(e - s, 1);
        float d0 = mean * linw[lane * 2 + 0];
        float d1 = mean * linw[lane * 2 + 1];
        for (int off = 32; off > 0; off >>= 1) {
            d0 += __shfl_down(d0, off);
            d1 += __shfl_down(d1, off);
        }
        if (lane == 0) {
            out[g * 2 + 0] = d0 + linb[0];
            out[g * 2 + 1] = d1 + linb[1];
        }
    }
}

extern "C" void kernel_launch(void* const* d_in, const int* in_sizes, int n_in,
                              void* d_out, int out_size, void* d_ws, size_t ws_size,
                              hipStream_t stream)
{
    const int*   x      = (const int*)d_in[0];
    const int*   ei     = (const int*)d_in[1];
    const int*   et     = (const int*)d_in[2];
    const int*   batch  = (const int*)d_in[3];
    const float* emb    = (const float*)d_in[4];
    const float* w1rel  = (const float*)d_in[5];
    const float* w1root = (const float*)d_in[6];
    const float* b1     = (const float*)d_in[7];
    const float* w2rel  = (const float*)d_in[8];
    const float* w2root = (const float*)d_in[9];
    const float* b2     = (const float*)d_in[10];
    const float* linw   = (const float*)d_in[11];
    const float* linb   = (const float*)d_in[12];
    float* out = (float*)d_out;

    const int N = in_sizes[0];            // 50000
    const int E = in_sizes[2];            // 1250000
    const int G = out_size / 2;           // 512
    const int NBKT = (N + 127) >> 7;      // 391
    const int NCHK = (E + CHUNK - 1) / CHUNK;  // 611

    float* hA        = (float*)d_ws;                     // [N][64]
    float* hB        = hA + (size_t)N * 64;              // [N][64]
    float* means     = hB + (size_t)N * 64;              // [N][192]
    int*   esort     = (int*)(means + (size_t)N * 192);  // [E]
    int*   rowstartR = esort + E;                        // [4N+4]
    int*   bucket_start = rowstartR + 4 * N + 4;         // [NBKT+1]
    int*   totals    = bucket_start + NBKT + 1;          // [NBKT]
    int*   scratch   = (int*)means;                      // sort scratch (12.8 MB)
    int*   pcount    = (int*)means + 4 * 1024 * 1024;    // [NCHK*NBKT]
    int*   pre       = (int*)means + 5 * 1024 * 1024;    // [NCHK*NBKT]

    int embedBlocks = (N * 16 + 255) / 256;              // 3125
    embed_count_kernel<<<embedBlocks + NCHK, 256, 0, stream>>>(
        x, emb, hA, ei, pcount, N, E, NBKT, embedBlocks);
    colscan_kernel<<<NBKT, 256, 0, stream>>>(pcount, pre, totals, rowstartR, NCHK, NBKT, E, N);
    scatter_kernel<<<NCHK, 256, 0, stream>>>(ei, et, pre, totals, esort, bucket_start, E, NBKT);
    bucket_sort_kernel<<<NBKT, 256, 0, stream>>>(bucket_start, esort, scratch, rowstartR, N);

    int aggBlocks = (N * 64 + 255) / 256;                // one wave per dst
    int tfBlocks  = ((N + 3) / 4 * 16 + 255) / 256;      // 4 nodes per thread
    agg_kernel<<<aggBlocks, 256, 0, stream>>>(hA, rowstartR, esort, means, N);
    transform_kernel<<<tfBlocks, 256, 0, stream>>>(hA, means, w1root, w1rel, b1, hB, N);
    agg_kernel<<<aggBlocks, 256, 0, stream>>>(hB, rowstartR, esort, means, N);
    transform_kernel<<<tfBlocks, 256, 0, stream>>>(hB, means, w2root, w2rel, b2, hA, N);

    pool_kernel<<<G, 256, 0, stream>>>(hA, batch, linw, linb, out, N, G);
}